// Round 9
// baseline (241.520 us; speedup 1.0000x reference)
//
#include <hip/hip_runtime.h>
#include <math.h>

// NN-MSE (one-directional Chamfer) via MFMA, 2 dispatches.
//
// d2(n,m) = |s_n|^2 + (|t_m|^2 - 2 s_n.t_m); cross term via
// v_mfma_f32_32x32x16_f16 (R8, verified absmax 0):
//   A lanes<32: [shx,shy,shz,slx,sly,slz,1,1] (fp16 hi/lo split src); >=32: 0
//   B col lane: [-2tx,-2ty,-2tz,-2tx,-2ty,-2tz,TNh,TNl] fp16, TN=|t|^2
//   C/D: col=lane&31, row=(reg&3)+8*(reg>>2)+4*(lane>>5)  [m74/m101]
//
// R9 restructure (R8 post-mortem: k1 ~8us, latency-chained main loop):
//  - wave owns ALL 4 src-tiles (4 afrags in regs) x 8 tgt-tiles:
//    8 ds_read_b128/wave issued up-front (one latency exposure), 32 MFMAs
//    back-to-back -> LDS ops 256->64 per CU, no per-iter stall chain.
//  - staging via coalesced float4 loads (3/thread vs 12 scalar).
//  - epilogue: shfl_xor(1,2) col-prereduce -> part[128][68] -> 4-thr combine.

#define THREADS 512
#define SRC_BLK 128
#define PSTRIDE 68       // floats; 17x16B-aligned, 2-way max on writes

typedef __attribute__((ext_vector_type(8))) _Float16 half8;
typedef __attribute__((ext_vector_type(16))) float f32x16;

__device__ __forceinline__ unsigned short f16b(float x) {
    _Float16 hv = (_Float16)x;
    return __builtin_bit_cast(unsigned short, hv);
}
__device__ __forceinline__ float f16tof(unsigned short u) {
    return (float)__builtin_bit_cast(_Float16, u);
}

__global__ __launch_bounds__(THREADS)
void nn_mfma_kernel(const float* __restrict__ coord,
                    const float* __restrict__ coord_t,
                    const float* __restrict__ Rm,
                    const float* __restrict__ tv,
                    float* __restrict__ ws,
                    int S, int NSC) {
    __shared__ uint4  Bfrag[2048];               // 32 KB
    __shared__ float  part[128 * PSTRIDE];       // 34 KB
    __shared__ float  SN_lds[128];
    __shared__ float  wsum8[8];

    const int tid  = threadIdx.x;
    const int bid  = blockIdx.x;
    const int b    = bid / NSC;
    const int sc   = bid - b * NSC;
    const int w    = tid >> 6;
    const int lane = tid & 63;
    const int col  = lane & 31;
    const int kh   = lane >> 5;

    // ---- stage B fragments: 4 consecutive targets/thread, float4 loads ----
    {
        const float* tb = coord_t + (size_t)b * S * 3;
        const float4* g4 = reinterpret_cast<const float4*>(tb) + (size_t)tid * 3;
        const float4 q0 = g4[0], q1 = g4[1], q2 = g4[2];
        const float px[4] = {q0.x, q0.w, q1.z, q2.y};
        const float py[4] = {q0.y, q1.x, q1.w, q2.z};
        const float pz[4] = {q0.z, q1.y, q2.x, q2.w};
        #pragma unroll
        for (int k = 0; k < 4; ++k) {
            const float tx = px[k], ty = py[k], tz = pz[k];
            const float TN = __builtin_fmaf(tz, tz, __builtin_fmaf(ty, ty, tx*tx));
            const unsigned uhx = f16b(-2.f*tx), uhy = f16b(-2.f*ty), uhz = f16b(-2.f*tz);
            const unsigned TNh = f16b(TN);
            const unsigned TNl = f16b(TN - f16tof((unsigned short)TNh));
            uint4 wv;
            wv.x = uhx | (uhy << 16);
            wv.y = uhz | (uhx << 16);
            wv.z = uhy | (uhz << 16);
            wv.w = TNh | (TNl << 16);
            Bfrag[tid * 4 + k] = wv;
        }
    }

    // ---- A fragments: 4 src-tiles per wave (all waves identical) ----
    half8 af[4];
    {
        const float* Rb = Rm + (size_t)b * 9;
        const float r00=Rb[0], r01=Rb[1], r02=Rb[2];
        const float r10=Rb[3], r11=Rb[4], r12=Rb[5];
        const float r20=Rb[6], r21=Rb[7], r22=Rb[8];
        const float t0=tv[3*b], t1=tv[3*b+1], t2=tv[3*b+2];
        #pragma unroll
        for (int st = 0; st < 4; ++st) {
            #pragma unroll
            for (int i = 0; i < 8; ++i) af[st][i] = (_Float16)0.0f;
            const float* sp = coord + ((size_t)b*S + (size_t)sc*SRC_BLK + st*32 + col) * 3;
            const float x = sp[0], y = sp[1], z = sp[2];
            const float sx = __builtin_fmaf(r00,x,__builtin_fmaf(r01,y,__builtin_fmaf(r02,z,t0)));
            const float sy = __builtin_fmaf(r10,x,__builtin_fmaf(r11,y,__builtin_fmaf(r12,z,t1)));
            const float sz = __builtin_fmaf(r20,x,__builtin_fmaf(r21,y,__builtin_fmaf(r22,z,t2)));
            if (w == 0 && kh == 0)
                SN_lds[st*32 + col] = __builtin_fmaf(sz, sz, __builtin_fmaf(sy, sy, sx*sx));
            if (kh == 0) {
                const _Float16 shx = (_Float16)sx, shy = (_Float16)sy, shz = (_Float16)sz;
                af[st][0] = shx; af[st][1] = shy; af[st][2] = shz;
                af[st][3] = (_Float16)(sx - (float)shx);
                af[st][4] = (_Float16)(sy - (float)shy);
                af[st][5] = (_Float16)(sz - (float)shz);
                af[st][6] = (_Float16)1.0f; af[st][7] = (_Float16)1.0f;
            }
        }
    }

    __syncthreads();

    // ---- read this wave's 8 B fragments up-front (one latency exposure) ----
    half8 bq[8];
    #pragma unroll
    for (int tt = 0; tt < 8; ++tt)
        bq[tt] = *reinterpret_cast<const half8*>(&Bfrag[(w*8 + tt)*32 + col]);

    // ---- 32 MFMAs, min3 merge into mn[4] ----
    f32x16 zf, mn[4];
    #pragma unroll
    for (int r = 0; r < 16; ++r) zf[r] = 0.0f;
    #pragma unroll
    for (int st = 0; st < 4; ++st) {
        #pragma unroll
        for (int r = 0; r < 16; ++r) mn[st][r] = 1e30f;
        #pragma unroll
        for (int tp = 0; tp < 4; ++tp) {
            const f32x16 aA = __builtin_amdgcn_mfma_f32_32x32x16_f16(af[st], bq[2*tp+0], zf, 0, 0, 0);
            const f32x16 aB = __builtin_amdgcn_mfma_f32_32x32x16_f16(af[st], bq[2*tp+1], zf, 0, 0, 0);
            #pragma unroll
            for (int r = 0; r < 16; ++r)
                mn[st][r] = fminf(fminf(mn[st][r], aA[r]), aB[r]);   // v_min3
        }
    }

    // ---- col prereduce to col%4, write part[src][w*8+cg] ----
    #pragma unroll
    for (int st = 0; st < 4; ++st) {
        #pragma unroll
        for (int r = 0; r < 16; ++r) {
            float v = mn[st][r];
            v = fminf(v, __shfl_xor(v, 1, 64));
            v = fminf(v, __shfl_xor(v, 2, 64));
            if ((lane & 3) == 0) {
                const int row = (r & 3) + 8*(r >> 2) + 4*kh;
                part[(st*32 + row)*PSTRIDE + (w << 3) + (col >> 2)] = v;
            }
        }
    }
    __syncthreads();

    // ---- combine: 4 threads/source over 64 partials; + |s|^2; block sum ----
    float v = 0.0f;
    {
        const int src = tid >> 2, ch = tid & 3;
        const float4* pp = reinterpret_cast<const float4*>(&part[src*PSTRIDE + ch*16]);
        const float4 q0 = pp[0], q1 = pp[1], q2 = pp[2], q3 = pp[3];
        float m = fminf(fminf(fminf(q0.x,q0.y), fminf(q0.z,q0.w)),
                        fminf(fminf(q1.x,q1.y), fminf(q1.z,q1.w)));
        m = fminf(m, fminf(fminf(fminf(q2.x,q2.y), fminf(q2.z,q2.w)),
                           fminf(fminf(q3.x,q3.y), fminf(q3.z,q3.w))));
        m = fminf(m, __shfl_xor(m, 1, 64));
        m = fminf(m, __shfl_xor(m, 2, 64));
        if (ch == 0) v = fmaxf(SN_lds[src] + m, 0.0f);
    }
    #pragma unroll
    for (int off = 32; off > 0; off >>= 1) v += __shfl_down(v, off, 64);
    if (lane == 0) wsum8[w] = v;
    __syncthreads();
    if (tid == 0) {
        float tot = 0.0f;
        #pragma unroll
        for (int i = 0; i < 8; ++i) tot += wsum8[i];
        ws[bid] = tot;
    }
}

__global__ __launch_bounds__(256)
void final_kernel(const float* __restrict__ partial, int n,
                  float* __restrict__ out, float scale) {
    float v = (threadIdx.x < n) ? partial[threadIdx.x] : 0.0f;
    #pragma unroll
    for (int off = 32; off > 0; off >>= 1) v += __shfl_down(v, off, 64);
    __shared__ float sm[4];
    if ((threadIdx.x & 63) == 0) sm[threadIdx.x >> 6] = v;
    __syncthreads();
    if (threadIdx.x == 0) out[0] = (sm[0] + sm[1] + sm[2] + sm[3]) * scale;
}

extern "C" void kernel_launch(void* const* d_in, const int* in_sizes, int n_in,
                              void* d_out, int out_size, void* d_ws, size_t ws_size,
                              hipStream_t stream) {
    const float* coord   = (const float*)d_in[0];
    const float* coord_t = (const float*)d_in[1];
    const float* Rm      = (const float*)d_in[2];
    const float* tv      = (const float*)d_in[3];

    const int B = in_sizes[2] / 9;            // R is [B,3,3]
    const int S = in_sizes[0] / (3 * B);      // coord is [B*S,3]; S assumed 2048
    const int NSC = S / SRC_BLK;              // 16
    const int nblk = B * NSC;                 // 256

    float* ws  = (float*)d_ws;
    float* out = (float*)d_out;

    nn_mfma_kernel<<<nblk, THREADS, 0, stream>>>(
        coord, coord_t, Rm, tv, ws, S, NSC);

    final_kernel<<<1, 256, 0, stream>>>(
        ws, nblk, out, 1.0f / ((float)B * (float)S));
}

// Round 10
// 37.640 us; speedup vs baseline: 6.4166x; 6.4166x over previous
//
#include <hip/hip_runtime.h>
#include <math.h>

// NN-MSE (one-directional Chamfer) via MFMA, 2 dispatches.
//
// d2(n,m) = |s_n|^2 + (|t_m|^2 - 2 s_n.t_m); cross term by
// v_mfma_f32_32x32x16_f16 with SWAPPED roles (R9 post-mortem: keep the
// per-source min in registers, not a 34KB LDS part[]):
//   A = targets (LDS uint4/target, both lane halves read same 8 halves ->
//       k8-15 duplicated, cancelled by B lanes>=32 == 0):
//       [-2tx,-2ty,-2tz,-2tx,-2ty,-2tz,TNh,TNl] fp16, TN=|t|^2 hi/lo
//   B = sources (regs, 4 VGPR/frag): kh==0 lanes [shx,shy,shz,slx,sly,slz,1,1]
//       (fp16 hi/lo split of transformed source), kh==1 lanes 0.
//   out(row=target,col=source); row=(reg&3)+8*(reg>>2)+4*kh, col=lane&31.
//   Per-source min = min3-tree over 16 regs + one shfl_xor(32) at the end.
//
// k1: 256 blocks x 512 thr. Wave w: af[8] = A-tiles w*8..w*8+7 (read once,
//     32 VGPR), bq[4] = 4 source-frags (128 sources, shared across waves),
//     32 MFMAs, best[4] running scalars. Epilogue: part[8][128] (4KB),
//     min over 8 waves, block sum -> ws. VGPR ~110, no spills.
// k2: sum 256 partials -> loss.

#define THREADS 512
#define SRC_BLK 128

typedef __attribute__((ext_vector_type(8))) _Float16 half8;
typedef __attribute__((ext_vector_type(16))) float f32x16;

__device__ __forceinline__ unsigned short f16b(float x) {
    _Float16 hv = (_Float16)x;
    return __builtin_bit_cast(unsigned short, hv);
}
__device__ __forceinline__ float f16tof(unsigned short u) {
    return (float)__builtin_bit_cast(_Float16, u);
}

__global__ __launch_bounds__(THREADS, 2)
void nn_mfma_kernel(const float* __restrict__ coord,
                    const float* __restrict__ coord_t,
                    const float* __restrict__ Rm,
                    const float* __restrict__ tv,
                    float* __restrict__ ws,
                    int S, int NSC) {
    __shared__ uint4  Afrag[2048];               // 32 KB: one entry/target
    __shared__ float  part[8 * SRC_BLK];         // 4 KB
    __shared__ float  wsum[2];

    const int tid  = threadIdx.x;
    const int bid  = blockIdx.x;
    const int b    = bid / NSC;
    const int sc   = bid - b * NSC;
    const int w    = tid >> 6;
    const int lane = tid & 63;
    const int col  = lane & 31;
    const int kh   = lane >> 5;

    // ---- stage target fragments: 4 consecutive targets/thread ----
    {
        const float* tb = coord_t + (size_t)b * S * 3;
        const float4* g4 = reinterpret_cast<const float4*>(tb) + (size_t)tid * 3;
        const float4 q0 = g4[0], q1 = g4[1], q2 = g4[2];
        const float px[4] = {q0.x, q0.w, q1.z, q2.y};
        const float py[4] = {q0.y, q1.x, q1.w, q2.z};
        const float pz[4] = {q0.z, q1.y, q2.x, q2.w};
        #pragma unroll
        for (int k = 0; k < 4; ++k) {
            const float tx = px[k], ty = py[k], tz = pz[k];
            const float TN = __builtin_fmaf(tz, tz, __builtin_fmaf(ty, ty, tx*tx));
            const unsigned uhx = f16b(-2.f*tx), uhy = f16b(-2.f*ty), uhz = f16b(-2.f*tz);
            const unsigned TNh = f16b(TN);
            const unsigned TNl = f16b(TN - f16tof((unsigned short)TNh));
            uint4 wv;
            wv.x = uhx | (uhy << 16);
            wv.y = uhz | (uhx << 16);
            wv.z = uhy | (uhz << 16);
            wv.w = TNh | (TNl << 16);
            Afrag[tid * 4 + k] = wv;
        }
    }

    // ---- B fragments: 4 source-frags (128 sources) per wave, in regs ----
    half8 bq[4];
    float SN[4];
    {
        const float* Rb = Rm + (size_t)b * 9;
        const float r00=Rb[0], r01=Rb[1], r02=Rb[2];
        const float r10=Rb[3], r11=Rb[4], r12=Rb[5];
        const float r20=Rb[6], r21=Rb[7], r22=Rb[8];
        const float t0=tv[3*b], t1=tv[3*b+1], t2=tv[3*b+2];
        #pragma unroll
        for (int bf = 0; bf < 4; ++bf) {
            #pragma unroll
            for (int i = 0; i < 8; ++i) bq[bf][i] = (_Float16)0.0f;
            const float* sp = coord + ((size_t)b*S + (size_t)sc*SRC_BLK + bf*32 + col) * 3;
            const float x = sp[0], y = sp[1], z = sp[2];
            const float sx = __builtin_fmaf(r00,x,__builtin_fmaf(r01,y,__builtin_fmaf(r02,z,t0)));
            const float sy = __builtin_fmaf(r10,x,__builtin_fmaf(r11,y,__builtin_fmaf(r12,z,t1)));
            const float sz = __builtin_fmaf(r20,x,__builtin_fmaf(r21,y,__builtin_fmaf(r22,z,t2)));
            SN[bf] = __builtin_fmaf(sz, sz, __builtin_fmaf(sy, sy, sx*sx));
            if (kh == 0) {
                const _Float16 shx = (_Float16)sx, shy = (_Float16)sy, shz = (_Float16)sz;
                bq[bf][0] = shx; bq[bf][1] = shy; bq[bf][2] = shz;
                bq[bf][3] = (_Float16)(sx - (float)shx);
                bq[bf][4] = (_Float16)(sy - (float)shy);
                bq[bf][5] = (_Float16)(sz - (float)shz);
                bq[bf][6] = (_Float16)1.0f; bq[bf][7] = (_Float16)1.0f;
            }
        }
    }

    __syncthreads();

    // ---- read this wave's 8 A-tiles up front (one latency exposure) ----
    half8 af[8];
    #pragma unroll
    for (int tt = 0; tt < 8; ++tt)
        af[tt] = *reinterpret_cast<const half8*>(&Afrag[(w*8 + tt)*32 + col]);

    // ---- 32 MFMAs; per-source min stays in registers ----
    f32x16 zf;
    #pragma unroll
    for (int r = 0; r < 16; ++r) zf[r] = 0.0f;
    float best[4] = {1e30f, 1e30f, 1e30f, 1e30f};

    #pragma unroll
    for (int tt = 0; tt < 8; ++tt) {
        #pragma unroll
        for (int bf = 0; bf < 4; bf += 2) {
            const f32x16 aA = __builtin_amdgcn_mfma_f32_32x32x16_f16(af[tt], bq[bf+0], zf, 0, 0, 0);
            const f32x16 aB = __builtin_amdgcn_mfma_f32_32x32x16_f16(af[tt], bq[bf+1], zf, 0, 0, 0);
            float mA = fminf(fminf(fminf(aA[0],aA[1]), fminf(aA[2],aA[3])),
                             fminf(fminf(aA[4],aA[5]), fminf(aA[6],aA[7])));
            mA = fminf(mA, fminf(fminf(fminf(aA[8],aA[9]), fminf(aA[10],aA[11])),
                                 fminf(fminf(aA[12],aA[13]), fminf(aA[14],aA[15]))));
            float mB = fminf(fminf(fminf(aB[0],aB[1]), fminf(aB[2],aB[3])),
                             fminf(fminf(aB[4],aB[5]), fminf(aB[6],aB[7])));
            mB = fminf(mB, fminf(fminf(fminf(aB[8],aB[9]), fminf(aB[10],aB[11])),
                                 fminf(fminf(aB[12],aB[13]), fminf(aB[14],aB[15]))));
            best[bf+0] = fminf(best[bf+0], mA);
            best[bf+1] = fminf(best[bf+1], mB);
        }
    }

    // ---- fold lane halves; +|s|^2; clamp; write tiny part[] ----
    #pragma unroll
    for (int bf = 0; bf < 4; ++bf) {
        best[bf] = fminf(best[bf], __shfl_xor(best[bf], 32, 64));
        if (kh == 0)
            part[w * SRC_BLK + bf*32 + col] = fmaxf(best[bf] + SN[bf], 0.0f);
    }
    __syncthreads();

    // ---- min over 8 waves per source; block sum ----
    float v = 0.0f;
    if (tid < SRC_BLK) {
        float m = part[tid];
        #pragma unroll
        for (int ww = 1; ww < 8; ++ww)
            m = fminf(m, part[ww * SRC_BLK + tid]);
        v = m;
    }
    if (tid < 128) {
        #pragma unroll
        for (int off = 32; off > 0; off >>= 1) v += __shfl_down(v, off, 64);
        if ((tid & 63) == 0) wsum[tid >> 6] = v;
    }
    __syncthreads();
    if (tid == 0) ws[bid] = wsum[0] + wsum[1];
}

__global__ __launch_bounds__(256)
void final_kernel(const float* __restrict__ partial, int n,
                  float* __restrict__ out, float scale) {
    float v = (threadIdx.x < n) ? partial[threadIdx.x] : 0.0f;
    #pragma unroll
    for (int off = 32; off > 0; off >>= 1) v += __shfl_down(v, off, 64);
    __shared__ float sm[4];
    if ((threadIdx.x & 63) == 0) sm[threadIdx.x >> 6] = v;
    __syncthreads();
    if (threadIdx.x == 0) out[0] = (sm[0] + sm[1] + sm[2] + sm[3]) * scale;
}

extern "C" void kernel_launch(void* const* d_in, const int* in_sizes, int n_in,
                              void* d_out, int out_size, void* d_ws, size_t ws_size,
                              hipStream_t stream) {
    const float* coord   = (const float*)d_in[0];
    const float* coord_t = (const float*)d_in[1];
    const float* Rm      = (const float*)d_in[2];
    const float* tv      = (const float*)d_in[3];

    const int B = in_sizes[2] / 9;            // R is [B,3,3]
    const int S = in_sizes[0] / (3 * B);      // coord is [B*S,3]
    const int NSC = S / SRC_BLK;              // 16
    const int nblk = B * NSC;                 // 256

    float* ws  = (float*)d_ws;
    float* out = (float*)d_out;

    nn_mfma_kernel<<<nblk, THREADS, 0, stream>>>(
        coord, coord_t, Rm, tv, ws, S, NSC);

    final_kernel<<<1, 256, 0, stream>>>(
        ws, nblk, out, 1.0f / ((float)B * (float)S));
}

// Round 11
// 13.128 us; speedup vs baseline: 18.3978x; 2.8672x over previous
//
#include <hip/hip_runtime.h>
#include <math.h>

// NN-MSE (one-directional Chamfer) via MFMA, 2 dispatches. R8 structure
// (12.2us, absmax 0) + two minimal k1 edits:
//  (1) S==2048 specialization: compile-time 16-trip main loop, unroll 4 ->
//      compiler pipelines the 8 ds_read_b128 per unrolled body ahead of the
//      MFMAs instead of exposing ~16 serial LDS latencies (R8 runtime bound).
//  (2) staging via 3 coalesced float4 loads/thread (was 12 scalar dwords).
// R9/R10 lesson: 512-thr blocks cap at 128 VGPR and spill silently; this
// structure peaks at ~100 live VGPRs (bq window = 8 frags = 32 regs).
//
// Math (verified R8): d2(n,m) = |s_n|^2 + (|t_m|^2 - 2 s_n.t_m); cross term
// by v_mfma_f32_32x32x16_f16:
//   A lanes<32: [shx,shy,shz,slx,sly,slz,1,1] (fp16 hi/lo split of src); >=32: 0
//   B col lane: [-2tx,-2ty,-2tz,-2tx,-2ty,-2tz,TNh,TNl] fp16, TN=|t|^2 hi/lo
//   C/D: col=lane&31, row=(reg&3)+8*(reg>>2)+4*(lane>>5)  [m74/m101]
//
// k1: 256 blocks x 512 thr (8 waves = 4 src-tiles x 2 target-halves).
//     Per-wave: one A-frag, 32 ds_read_b128 B-frags, 32 MFMAs, min3 into
//     f32x16 mn; shfl_xor(1,2) col prereduce -> part[] (stride 18) ->
//     combine + block sum -> ws.
// k2: sum 256 partials -> loss.

#define THREADS 512
#define SRC_BLK 128
#define PART_STRIDE 18

typedef __attribute__((ext_vector_type(8))) _Float16 half8;
typedef __attribute__((ext_vector_type(16))) float f32x16;

__device__ __forceinline__ unsigned short f16b(float x) {
    _Float16 hv = (_Float16)x;
    return __builtin_bit_cast(unsigned short, hv);
}
__device__ __forceinline__ float f16tof(unsigned short u) {
    return (float)__builtin_bit_cast(_Float16, u);
}

__global__ __launch_bounds__(THREADS)
void nn_mfma_kernel(const float* __restrict__ coord,
                    const float* __restrict__ coord_t,
                    const float* __restrict__ Rm,
                    const float* __restrict__ tv,
                    float* __restrict__ ws,
                    int S, int NSC) {
    __shared__ uint4 Bfrag[2048];                 // 32 KB: one 16B entry/target
    __shared__ float part[128 * PART_STRIDE];     // 9 KB, padded stride
    __shared__ float SN_lds[128];
    __shared__ float wsum[2];

    const int tid  = threadIdx.x;
    const int bid  = blockIdx.x;
    const int b    = bid / NSC;
    const int sc   = bid - b * NSC;
    const int w    = tid >> 6;
    const int lane = tid & 63;
    const int col  = lane & 31;
    const int kh   = lane >> 5;
    const int wsrc = w >> 1;      // src-tile 0..3
    const int h    = w & 1;       // target half 0..1

    // ---- stage B fragments: 4 consecutive targets/thread, float4 loads ----
    if (tid * 4 < S) {
        const float* tb = coord_t + (size_t)b * S * 3;
        const float4* g4 = reinterpret_cast<const float4*>(tb) + (size_t)tid * 3;
        const float4 q0 = g4[0], q1 = g4[1], q2 = g4[2];
        const float px[4] = {q0.x, q0.w, q1.z, q2.y};
        const float py[4] = {q0.y, q1.x, q1.w, q2.z};
        const float pz[4] = {q0.z, q1.y, q2.x, q2.w};
        #pragma unroll
        for (int k = 0; k < 4; ++k) {
            const float tx = px[k], ty = py[k], tz = pz[k];
            const float TN = __builtin_fmaf(tz, tz, __builtin_fmaf(ty, ty, tx*tx));
            const unsigned uhx = f16b(-2.f*tx), uhy = f16b(-2.f*ty), uhz = f16b(-2.f*tz);
            const unsigned TNh = f16b(TN);
            const unsigned TNl = f16b(TN - f16tof((unsigned short)TNh));
            uint4 wv;
            wv.x = uhx | (uhy << 16);
            wv.y = uhz | (uhx << 16);
            wv.z = uhy | (uhz << 16);
            wv.w = TNh | (TNl << 16);
            Bfrag[tid * 4 + k] = wv;
        }
    }

    // ---- A fragment: transformed source, fp16 hi/lo split ----
    half8 afrag;
    #pragma unroll
    for (int i = 0; i < 8; ++i) afrag[i] = (_Float16)0.0f;
    {
        const float* Rb = Rm + (size_t)b * 9;
        const float r00=Rb[0], r01=Rb[1], r02=Rb[2];
        const float r10=Rb[3], r11=Rb[4], r12=Rb[5];
        const float r20=Rb[6], r21=Rb[7], r22=Rb[8];
        const float t0=tv[3*b], t1=tv[3*b+1], t2=tv[3*b+2];

        const float* sp = coord + ((size_t)b*S + (size_t)sc*SRC_BLK + wsrc*32 + col) * 3;
        const float x = sp[0], y = sp[1], z = sp[2];
        const float sx = __builtin_fmaf(r00,x,__builtin_fmaf(r01,y,__builtin_fmaf(r02,z,t0)));
        const float sy = __builtin_fmaf(r10,x,__builtin_fmaf(r11,y,__builtin_fmaf(r12,z,t1)));
        const float sz = __builtin_fmaf(r20,x,__builtin_fmaf(r21,y,__builtin_fmaf(r22,z,t2)));
        const float SN = __builtin_fmaf(sz, sz, __builtin_fmaf(sy, sy, sx*sx));
        if (h == 0 && kh == 0) SN_lds[wsrc*32 + col] = SN;
        if (kh == 0) {
            const _Float16 shx = (_Float16)sx, shy = (_Float16)sy, shz = (_Float16)sz;
            afrag[0] = shx; afrag[1] = shy; afrag[2] = shz;
            afrag[3] = (_Float16)(sx - (float)shx);
            afrag[4] = (_Float16)(sy - (float)shy);
            afrag[5] = (_Float16)(sz - (float)shz);
            afrag[6] = (_Float16)1.0f; afrag[7] = (_Float16)1.0f;
        }
    }

    __syncthreads();

    // ---- main loop: 32 target tiles per wave, 2 per iteration ----
    f32x16 zf, mn;
    #pragma unroll
    for (int r = 0; r < 16; ++r) { zf[r] = 0.0f; mn[r] = 1e30f; }

    const uint4* Bp = &Bfrag[h*1024 + col];
    if (S == 2048) {
        #pragma unroll 4
        for (int it = 0; it < 16; ++it) {
            const half8 b0 = *reinterpret_cast<const half8*>(Bp + it*64);
            const half8 b1 = *reinterpret_cast<const half8*>(Bp + it*64 + 32);
            const f32x16 aA = __builtin_amdgcn_mfma_f32_32x32x16_f16(afrag, b0, zf, 0, 0, 0);
            const f32x16 aB = __builtin_amdgcn_mfma_f32_32x32x16_f16(afrag, b1, zf, 0, 0, 0);
            #pragma unroll
            for (int r = 0; r < 16; ++r)
                mn[r] = fminf(fminf(mn[r], aA[r]), aB[r]);    // v_min3
        }
    } else {
        const int nit = S >> 7;
        for (int it = 0; it < nit; ++it) {
            const half8 b0 = *reinterpret_cast<const half8*>(Bp + it*64);
            const half8 b1 = *reinterpret_cast<const half8*>(Bp + it*64 + 32);
            const f32x16 aA = __builtin_amdgcn_mfma_f32_32x32x16_f16(afrag, b0, zf, 0, 0, 0);
            const f32x16 aB = __builtin_amdgcn_mfma_f32_32x32x16_f16(afrag, b1, zf, 0, 0, 0);
            #pragma unroll
            for (int r = 0; r < 16; ++r)
                mn[r] = fminf(fminf(mn[r], aA[r]), aB[r]);
        }
    }

    // ---- col prereduce (groups of 4) + write to padded part[] ----
    #pragma unroll
    for (int r = 0; r < 16; ++r) {
        float v = mn[r];
        v = fminf(v, __shfl_xor(v, 1, 64));
        v = fminf(v, __shfl_xor(v, 2, 64));
        if ((col & 3) == 0) {
            const int row = (r & 3) + 8*(r >> 2) + 4*kh;
            part[(wsrc*32 + row)*PART_STRIDE + h*8 + (col >> 2)] = v;
        }
    }
    __syncthreads();

    // ---- combine 16 partials/source, add |s|^2, clamp, block sum ----
    float acc = 0.0f;
    if (tid < 128) {
        const float* pp = &part[tid * PART_STRIDE];
        float m = pp[0];
        #pragma unroll
        for (int j = 1; j < 16; ++j) m = fminf(m, pp[j]);
        acc = fmaxf(SN_lds[tid] + m, 0.0f);
        #pragma unroll
        for (int off = 32; off > 0; off >>= 1) acc += __shfl_down(acc, off, 64);
        if ((tid & 63) == 0) wsum[tid >> 6] = acc;
    }
    __syncthreads();
    if (tid == 0) ws[bid] = wsum[0] + wsum[1];
}

__global__ __launch_bounds__(256)
void final_kernel(const float* __restrict__ partial, int n,
                  float* __restrict__ out, float scale) {
    float v = (threadIdx.x < n) ? partial[threadIdx.x] : 0.0f;
    #pragma unroll
    for (int off = 32; off > 0; off >>= 1) v += __shfl_down(v, off, 64);
    __shared__ float sm[4];
    if ((threadIdx.x & 63) == 0) sm[threadIdx.x >> 6] = v;
    __syncthreads();
    if (threadIdx.x == 0) out[0] = (sm[0] + sm[1] + sm[2] + sm[3]) * scale;
}

extern "C" void kernel_launch(void* const* d_in, const int* in_sizes, int n_in,
                              void* d_out, int out_size, void* d_ws, size_t ws_size,
                              hipStream_t stream) {
    const float* coord   = (const float*)d_in[0];
    const float* coord_t = (const float*)d_in[1];
    const float* Rm      = (const float*)d_in[2];
    const float* tv      = (const float*)d_in[3];

    const int B = in_sizes[2] / 9;            // R is [B,3,3]
    const int S = in_sizes[0] / (3 * B);      // coord is [B*S,3]
    const int NSC = S / SRC_BLK;              // 16
    const int nblk = B * NSC;                 // 256

    float* ws  = (float*)d_ws;
    float* out = (float*)d_out;

    nn_mfma_kernel<<<nblk, THREADS, 0, stream>>>(
        coord, coord_t, Rm, tv, ws, S, NSC);

    final_kernel<<<1, 256, 0, stream>>>(
        ws, nblk, out, 1.0f / ((float)B * (float)S));
}